// Round 4
// baseline (313.036 us; speedup 1.0000x reference)
//
#include <hip/hip_runtime.h>
#include <hip/hip_bf16.h>
#include <stdint.h>

#define Bb   8
#define Tt   2048
#define Cdim 1024
#define BT   16384   // Bb*Tt
#define SLAB ((size_t)BT * Cdim)

// chunked WKV scan geometry
#define NC   64            // chunks per chain
#define LCH  32            // Tt / NC
#define CSUB 16            // channels per block

typedef __attribute__((ext_vector_type(4))) float f32x4;
typedef __attribute__((ext_vector_type(8))) short bf16x8;

__device__ inline short f2bs(float f) {
    union { __hip_bfloat16 h; short s; } u;
    u.h = __float2bfloat16(f);
    return u.s;
}
__device__ inline float bs2f(short s) {
    union { short s; __hip_bfloat16 h; } u;
    u.s = s;
    return __bfloat162float(u.h);
}

#define GLOAD_LDS16(g, l) __builtin_amdgcn_global_load_lds( \
    (const __attribute__((address_space(1))) void*)(g),     \
    (__attribute__((address_space(3))) void*)(l), 16, 0, 0)

#define SBAR()      __builtin_amdgcn_s_barrier()
#define WAIT_LGKM0  asm volatile("s_waitcnt lgkmcnt(0)" ::: "memory")

// ---------------------------------------------------------------------------
// prep_x: xmix[z][m][c] = lerp(x_prev, x, mix_z)  (bf16), z in {k,v,r}
// ---------------------------------------------------------------------------
__global__ __launch_bounds__(256) void prep_x(
    const float* __restrict__ x,
    const float* __restrict__ mk,
    const float* __restrict__ mv,
    const float* __restrict__ mr,
    short* __restrict__ xmix)
{
    int idx = blockIdx.x * 256 + threadIdx.x;   // [0, BT*Cdim/8)
    int c8  = idx & (Cdim / 8 - 1);
    int m   = idx >> 7;                          // Cdim/8 == 128
    int c0  = c8 << 3;
    int t   = m & (Tt - 1);

    float xs[8], ps[8];
    const float4* xp = (const float4*)(x + (size_t)m * Cdim + c0);
    float4 xa = xp[0], xb = xp[1];
    xs[0]=xa.x; xs[1]=xa.y; xs[2]=xa.z; xs[3]=xa.w;
    xs[4]=xb.x; xs[5]=xb.y; xs[6]=xb.z; xs[7]=xb.w;
    if (t != 0) {
        const float4* pp = (const float4*)(x + (size_t)(m - 1) * Cdim + c0);
        float4 pa = pp[0], pb = pp[1];
        ps[0]=pa.x; ps[1]=pa.y; ps[2]=pa.z; ps[3]=pa.w;
        ps[4]=pb.x; ps[5]=pb.y; ps[6]=pb.z; ps[7]=pb.w;
    } else {
        #pragma unroll
        for (int j = 0; j < 8; ++j) ps[j] = 0.f;
    }

    const float* mixes[3] = {mk, mv, mr};
    #pragma unroll
    for (int z = 0; z < 3; ++z) {
        const float4* mp = (const float4*)(mixes[z] + c0);
        float4 ma = mp[0], mb = mp[1];
        float mm[8];
        mm[0]=ma.x; mm[1]=ma.y; mm[2]=ma.z; mm[3]=ma.w;
        mm[4]=mb.x; mm[5]=mb.y; mm[6]=mb.z; mm[7]=mb.w;
        bf16x8 o;
        #pragma unroll
        for (int j = 0; j < 8; ++j)
            o[j] = f2bs(ps[j] + mm[j] * (xs[j] - ps[j]));
        *(bf16x8*)(xmix + (size_t)z * SLAB + (size_t)m * Cdim + c0) = o;
    }
}

// ---------------------------------------------------------------------------
// prep_w: Wk|Wv|Wr|Wo f32 -> bf16, concatenated [4][C][C]
// ---------------------------------------------------------------------------
__global__ __launch_bounds__(256) void prep_w(
    const float* __restrict__ Wk, const float* __restrict__ Wv,
    const float* __restrict__ Wr, const float* __restrict__ Wo,
    short* __restrict__ wbf)
{
    int idx = blockIdx.x * 256 + threadIdx.x;       // [0, 4*C*C/8)
    int z   = idx >> 17;                            // C*C/8 == 131072
    int r   = idx & (Cdim * Cdim / 8 - 1);
    const float* src = (z == 0) ? Wk : (z == 1) ? Wv : (z == 2) ? Wr : Wo;
    const float4* sp = (const float4*)(src + (size_t)r * 8);
    float4 a = sp[0], b = sp[1];
    float v[8] = {a.x, a.y, a.z, a.w, b.x, b.y, b.z, b.w};
    bf16x8 o;
    #pragma unroll
    for (int j = 0; j < 8; ++j) o[j] = f2bs(v[j]);
    *(bf16x8*)(wbf + (size_t)z * Cdim * Cdim + (size_t)r * 8) = o;
}

// ---------------------------------------------------------------------------
// gemm256<FUSED>: 256x256 tile, BK=32, 8 waves (2Mx4N), quad-buffered LDS,
// 2 phases/K-tile, stage lead = 3 tiles, counted vmcnt(8) (T3+T4),
// XOR-swizzled LDS (T2, conflict-free verified), setprio (T5),
// XCD-chunked bijective blockIdx swizzle (T1).
// FUSED=1: grid (12,64); block z = n-group selects {xmix slab, W slab, output}
//          z==2 applies sigmoid; bf16 stores.
// FUSED=0: grid (4,64); f32 stores to o0.
// ---------------------------------------------------------------------------
template<int FUSED>
__global__ __launch_bounds__(512, 2) void gemm256(
    const short* __restrict__ Abase,   // FUSED: xmix[3][BT][C]; else rwkv
    const short* __restrict__ Wbase,   // FUSED: wbf[0..2];      else wbf+3*C*C
    void* __restrict__ o0, void* __restrict__ o1, void* __restrict__ o2)
{
    __shared__ __align__(16) short lds[65536];   // 128 KiB: 4 bufs x (A 8KB | B 8KB) shorts

    const int tid  = threadIdx.x;
    const int lane = tid & 63;
    const int wv   = tid >> 6;
    const int wm   = wv >> 2, wn = wv & 3;       // 2 x 4 waves
    const int NT   = Cdim / 32;                  // 32 K-tiles

    // T1: XCD-chunked bijective remap (nwg % 8 == 0 for both grids)
    int orig = blockIdx.y * gridDim.x + blockIdx.x;
    int nwg  = gridDim.x * gridDim.y;
    int wid  = (orig & 7) * (nwg >> 3) + (orig >> 3);

    int yt, nt, z;
    if (FUSED) { yt = wid / 12; int xt = wid % 12; z = xt >> 2; nt = xt & 3; }
    else       { yt = wid >> 2; nt = wid & 3; z = 0; }

    const short* A  = Abase + (size_t)z * SLAB;
    const short* Bm = Wbase + (size_t)z * Cdim * Cdim;
    const int m0 = yt * 256;
    const int n0 = nt * 256;

    f32x4 acc[8][4] = {};

    // per-lane fragment offsets within a buffer (shorts), swizzled
    int a_off[8], b_off[4];
    #pragma unroll
    for (int i = 0; i < 8; ++i) {
        int r = wm * 128 + i * 16 + (lane & 15);
        a_off[i] = r * 32 + ((((lane >> 4) ^ ((r >> 1) & 3))) << 3);
    }
    #pragma unroll
    for (int j = 0; j < 4; ++j) {
        int r = wn * 64 + j * 16 + (lane & 15);
        b_off[j] = r * 32 + ((((lane >> 4) ^ ((r >> 1) & 3))) << 3);
    }

    // stage part p (0,1 = A halves; 2,3 = B halves) of K-tile tt.
    auto STAGE = [&](int tt, int p) {
        int row = ((p & 1) << 7) + (tid >> 2);          // 0..255 within tile
        int cc  = (tid & 3) ^ ((row >> 1) & 3);
        const short* g = ((p < 2) ? (A + (size_t)(m0 + row) * Cdim)
                                  : (Bm + (size_t)(n0 + row) * Cdim))
                         + (tt << 5) + (cc << 3);
        short* l = lds + ((tt & 3) << 14) + ((p < 2) ? 0 : 8192)
                       + ((p & 1) << 12) + tid * 8;
        GLOAD_LDS16(g, l);
    };

    // prologue: stage tiles 0,1,2 (12 loads/thread), wait tile0, barrier
    #pragma unroll
    for (int p = 0; p < 4; ++p) STAGE(0, p);
    #pragma unroll
    for (int p = 0; p < 4; ++p) STAGE(1, p);
    #pragma unroll
    for (int p = 0; p < 4; ++p) STAGE(2, p);
    asm volatile("s_waitcnt vmcnt(8)" ::: "memory");
    SBAR();

    #pragma unroll 1
    for (int kt = 0; kt < NT; ++kt) {
        const short* la = lds + ((kt & 3) << 14);
        const short* lb = la + 8192;
        const bool st = (kt + 3) < NT;

        // ---- phase 0: A frags 0-3 + all B frags; MFMA m0-3 x n0-3 ----
        bf16x8 afr[4], bfr[4];
        #pragma unroll
        for (int i = 0; i < 4; ++i) afr[i] = *(const bf16x8*)(la + a_off[i]);
        #pragma unroll
        for (int j = 0; j < 4; ++j) bfr[j] = *(const bf16x8*)(lb + b_off[j]);
        if (st) { STAGE(kt + 3, 0); STAGE(kt + 3, 1); }
        SBAR();
        WAIT_LGKM0;
        __builtin_amdgcn_sched_barrier(0);
        __builtin_amdgcn_s_setprio(1);
        #pragma unroll
        for (int i = 0; i < 4; ++i)
            #pragma unroll
            for (int j = 0; j < 4; ++j)
                acc[i][j] = __builtin_amdgcn_mfma_f32_16x16x32_bf16(
                    afr[i], bfr[j], acc[i][j], 0, 0, 0);
        __builtin_amdgcn_s_setprio(0);
        SBAR();

        // ---- phase 1: A frags 4-7; MFMA m4-7 x n0-3 ----
        bf16x8 af2[4];
        #pragma unroll
        for (int i = 0; i < 4; ++i) af2[i] = *(const bf16x8*)(la + a_off[i + 4]);
        if (st) { STAGE(kt + 3, 2); STAGE(kt + 3, 3); }
        SBAR();
        WAIT_LGKM0;
        __builtin_amdgcn_sched_barrier(0);
        __builtin_amdgcn_s_setprio(1);
        #pragma unroll
        for (int i = 0; i < 4; ++i)
            #pragma unroll
            for (int j = 0; j < 4; ++j)
                acc[i + 4][j] = __builtin_amdgcn_mfma_f32_16x16x32_bf16(
                    af2[i], bfr[j], acc[i + 4][j], 0, 0, 0);
        __builtin_amdgcn_s_setprio(0);
        // counted vmcnt: tile kt+1 must be resident; tiles kt+2, kt+3 in flight.
        if      (kt <  NT - 3) { asm volatile("s_waitcnt vmcnt(8)" ::: "memory"); }
        else if (kt == NT - 3) { asm volatile("s_waitcnt vmcnt(4)" ::: "memory"); }
        else if (kt == NT - 2) { asm volatile("s_waitcnt vmcnt(0)" ::: "memory"); }
        SBAR();
    }

    // epilogue: C/D layout col = lane&15, row = (lane>>4)*4 + r  [m89]
    int col0 = n0 + wn * 64 + (lane & 15);
    int row0 = m0 + wm * 128 + ((lane >> 4) << 2);
    short* outb = 0;
    if (FUSED) outb = (short*)((z == 0) ? o0 : (z == 1) ? o1 : o2);
    #pragma unroll
    for (int i = 0; i < 8; ++i) {
        #pragma unroll
        for (int j = 0; j < 4; ++j) {
            #pragma unroll
            for (int r = 0; r < 4; ++r) {
                int row = row0 + i * 16 + r;
                int cc  = col0 + j * 16;
                float vvv = acc[i][j][r];
                if (FUSED) {
                    if (z == 2) vvv = 1.f / (1.f + __expf(-vvv));
                    outb[(size_t)row * Cdim + cc] = f2bs(vvv);
                } else {
                    ((float*)o0)[(size_t)row * Cdim + cc] = vvv;
                }
            }
        }
    }
}

// ---------------------------------------------------------------------------
// wkv_chunked: chunked-parallel stable WKV scan; r is PRE-SIGMOIDED bf16.
// Block: CSUB=16 channels x NC=64 chunks = 1024 threads; grid = Bb * Cdim/16.
// ---------------------------------------------------------------------------
__global__ __launch_bounds__(1024) void wkv_chunked(
    const short* __restrict__ kb, const short* __restrict__ vb,
    const short* __restrict__ srb,
    const float* __restrict__ w, const float* __restrict__ u,
    short* __restrict__ rwkv)
{
    __shared__ float sp[NC][CSUB];
    __shared__ float sq[NC][CSUB];
    __shared__ float so[NC][CSUB];

    int tid = threadIdx.x;
    int cl  = tid & (CSUB - 1);
    int ch  = tid >> 4;                 // chunk index 0..NC-1
    int b   = blockIdx.x >> 6;          // grid = Bb * (Cdim/CSUB) = 8*64
    int cg  = blockIdx.x & 63;
    int c   = cg * CSUB + cl;

    float wexp = -__expf(w[c]);
    float uu   = u[c];
    size_t coff = (size_t)b * Tt * Cdim + (size_t)(ch * LCH) * Cdim + c;

    // ---- phase 1: local chunk summary from zero state ----
    float p = 0.f, q = 0.f, o = -1e30f;
    #pragma unroll 8
    for (int t = 0; t < LCH; ++t) {
        size_t off = coff + (size_t)t * Cdim;
        float kt = bs2f(kb[off]);
        float vt = bs2f(vb[off]);
        float wo  = wexp + o;
        float no  = fmaxf(wo, kt);
        float A   = __expf(wo - no);
        float B2  = __expf(kt - no);
        p = A * p + B2 * vt;
        q = A * q + B2;
        o = no;
    }
    sp[ch][cl] = p; sq[ch][cl] = q; so[ch][cl] = o;
    __syncthreads();

    // ---- phase 2: exclusive combine-scan over chunks (1 thread / channel) ----
    if (tid < CSUB) {
        float Ld = wexp * (float)LCH;   // decay of o over a full chunk
        float cp = 0.f, cq = 0.f, co = -1e30f;
        #pragma unroll 8
        for (int j = 0; j < NC; ++j) {
            float lp = sp[j][tid], lq = sq[j][tid], lo = so[j][tid];
            sp[j][tid] = cp; sq[j][tid] = cq; so[j][tid] = co;  // incoming state
            float od = co + Ld;
            float no = fmaxf(od, lo);
            float A  = __expf(od - no);
            float B2 = __expf(lo - no);
            cp = A * cp + B2 * lp;
            cq = A * cq + B2 * lq;
            co = no;
        }
    }
    __syncthreads();

    // ---- phase 3: outputs from incoming state ----
    p = sp[ch][cl]; q = sq[ch][cl]; o = so[ch][cl];
    #pragma unroll 8
    for (int t = 0; t < LCH; ++t) {
        size_t off = coff + (size_t)t * Cdim;
        float kt = bs2f(kb[off]);
        float vt = bs2f(vb[off]);
        float sr = bs2f(srb[off]);       // sigmoid already applied in GEMM

        float uk  = uu + kt;
        float no  = fmaxf(o, uk);
        float Aa  = __expf(o - no);
        float Bc  = __expf(uk - no);
        float out = (Aa * p + Bc * vt) / (Aa * q + Bc);

        float wo  = wexp + o;
        float no2 = fmaxf(wo, kt);
        float A2  = __expf(wo - no2);
        float B2  = __expf(kt - no2);
        p = A2 * p + B2 * vt;
        q = A2 * q + B2;
        o = no2;

        rwkv[off] = f2bs(sr * out);
    }
}

// ---------------------------------------------------------------------------
extern "C" void kernel_launch(void* const* d_in, const int* in_sizes, int n_in,
                              void* d_out, int out_size, void* d_ws, size_t ws_size,
                              hipStream_t stream)
{
    const float* x    = (const float*)d_in[0];
    const float* w    = (const float*)d_in[1];
    const float* u    = (const float*)d_in[2];
    const float* mixk = (const float*)d_in[3];
    const float* mixv = (const float*)d_in[4];
    const float* mixr = (const float*)d_in[5];
    const float* Wk   = (const float*)d_in[6];
    const float* Wv   = (const float*)d_in[7];
    const float* Wr   = (const float*)d_in[8];
    const float* Wo   = (const float*)d_in[9];

    char* ws = (char*)d_ws;
    short* xmix = (short*)ws;                        // 3 slabs bf16 = 96 MiB
    short* wbf  = (short*)(ws + 3 * SLAB * 2);       // 4*C*C bf16 = 8 MiB
    short* rbuf = (short*)(ws + 3 * SLAB * 2 + (size_t)4 * Cdim * Cdim * 2); // 32 MiB
    short* rwkv = (short*)ws;                        // reuses dead xmix slab 0
    short* kbuf = (short*)d_out;                     // k,v bf16 live in d_out
    short* vbuf = kbuf + SLAB;                       // exactly fills 64 MiB

    prep_x<<<BT * Cdim / 8 / 256, 256, 0, stream>>>(x, mixk, mixv, mixr, xmix);
    prep_w<<<4 * Cdim * Cdim / 8 / 256, 256, 0, stream>>>(Wk, Wv, Wr, Wo, wbf);

    // fused k/v/r GEMM: grid (12,64) = 768 blocks
    dim3 gf(12, BT / 256);
    gemm256<1><<<gf, 512, 0, stream>>>(xmix, wbf, kbuf, vbuf, rbuf);

    wkv_chunked<<<Bb * (Cdim / CSUB), 1024, 0, stream>>>(kbuf, vbuf, rbuf, w, u, rwkv);

    // output GEMM: grid (4,64) = 256 blocks, f32 out
    dim3 go(Cdim / 256, BT / 256);
    gemm256<0><<<go, 512, 0, stream>>>(rwkv, wbf + 3 * (size_t)Cdim * Cdim,
                                       (float*)d_out, nullptr, nullptr);
}

// Round 5
// 255.918 us; speedup vs baseline: 1.2232x; 1.2232x over previous
//
#include <hip/hip_runtime.h>
#include <hip/hip_bf16.h>
#include <stdint.h>

#define Bb   8
#define Tt   2048
#define Cdim 1024
#define BT   16384   // Bb*Tt
#define SLAB ((size_t)BT * Cdim)

// chunked WKV scan geometry (round-3 proven: 66 us)
#define NC   32            // chunks per chain
#define LCH  64            // Tt / NC
#define CSUB 32            // channels per block

typedef __attribute__((ext_vector_type(4))) float f32x4;
typedef __attribute__((ext_vector_type(8))) short bf16x8;

__device__ inline short f2bs(float f) {
    union { __hip_bfloat16 h; short s; } u;
    u.h = __float2bfloat16(f);
    return u.s;
}
__device__ inline float bs2f(short s) {
    union { short s; __hip_bfloat16 h; } u;
    u.s = s;
    return __bfloat162float(u.h);
}

#define GLOAD_LDS16(g, l) __builtin_amdgcn_global_load_lds( \
    (const __attribute__((address_space(1))) void*)(g),     \
    (__attribute__((address_space(3))) void*)(l), 16, 0, 0)

#define SBAR()      __builtin_amdgcn_s_barrier()
#define WAIT_LGKM0  asm volatile("s_waitcnt lgkmcnt(0)" ::: "memory")
#define SCHEDB()    __builtin_amdgcn_sched_barrier(0)

// ---------------------------------------------------------------------------
// prep_x: xmix[z][m][c] = lerp(x_prev, x, mix_z)  (bf16), z in {k,v,r}
// ---------------------------------------------------------------------------
__global__ __launch_bounds__(256) void prep_x(
    const float* __restrict__ x,
    const float* __restrict__ mk,
    const float* __restrict__ mv,
    const float* __restrict__ mr,
    short* __restrict__ xmix)
{
    int idx = blockIdx.x * 256 + threadIdx.x;   // [0, BT*Cdim/8)
    int c8  = idx & (Cdim / 8 - 1);
    int m   = idx >> 7;                          // Cdim/8 == 128
    int c0  = c8 << 3;
    int t   = m & (Tt - 1);

    float xs[8], ps[8];
    const float4* xp = (const float4*)(x + (size_t)m * Cdim + c0);
    float4 xa = xp[0], xb = xp[1];
    xs[0]=xa.x; xs[1]=xa.y; xs[2]=xa.z; xs[3]=xa.w;
    xs[4]=xb.x; xs[5]=xb.y; xs[6]=xb.z; xs[7]=xb.w;
    if (t != 0) {
        const float4* pp = (const float4*)(x + (size_t)(m - 1) * Cdim + c0);
        float4 pa = pp[0], pb = pp[1];
        ps[0]=pa.x; ps[1]=pa.y; ps[2]=pa.z; ps[3]=pa.w;
        ps[4]=pb.x; ps[5]=pb.y; ps[6]=pb.z; ps[7]=pb.w;
    } else {
        #pragma unroll
        for (int j = 0; j < 8; ++j) ps[j] = 0.f;
    }

    const float* mixes[3] = {mk, mv, mr};
    #pragma unroll
    for (int z = 0; z < 3; ++z) {
        const float4* mp = (const float4*)(mixes[z] + c0);
        float4 ma = mp[0], mb = mp[1];
        float mm[8];
        mm[0]=ma.x; mm[1]=ma.y; mm[2]=ma.z; mm[3]=ma.w;
        mm[4]=mb.x; mm[5]=mb.y; mm[6]=mb.z; mm[7]=mb.w;
        bf16x8 o;
        #pragma unroll
        for (int j = 0; j < 8; ++j)
            o[j] = f2bs(ps[j] + mm[j] * (xs[j] - ps[j]));
        *(bf16x8*)(xmix + (size_t)z * SLAB + (size_t)m * Cdim + c0) = o;
    }
}

// ---------------------------------------------------------------------------
// prep_w: Wk|Wv|Wr|Wo f32 -> bf16, concatenated [4][C][C]
// ---------------------------------------------------------------------------
__global__ __launch_bounds__(256) void prep_w(
    const float* __restrict__ Wk, const float* __restrict__ Wv,
    const float* __restrict__ Wr, const float* __restrict__ Wo,
    short* __restrict__ wbf)
{
    int idx = blockIdx.x * 256 + threadIdx.x;       // [0, 4*C*C/8)
    int z   = idx >> 17;                            // C*C/8 == 131072
    int r   = idx & (Cdim * Cdim / 8 - 1);
    const float* src = (z == 0) ? Wk : (z == 1) ? Wv : (z == 2) ? Wr : Wo;
    const float4* sp = (const float4*)(src + (size_t)r * 8);
    float4 a = sp[0], b = sp[1];
    float v[8] = {a.x, a.y, a.z, a.w, b.x, b.y, b.z, b.w};
    bf16x8 o;
    #pragma unroll
    for (int j = 0; j < 8; ++j) o[j] = f2bs(v[j]);
    *(bf16x8*)(wbf + (size_t)z * Cdim * Cdim + (size_t)r * 8) = o;
}

// ---------------------------------------------------------------------------
// gemm256: m201-style 8-phase schedule. 256x256 tile, BK=64, 8 waves (2Mx4N),
// double-buffered LDS (2 x 64KB), 4 phases per K-tile, snake quadrant order,
// counted vmcnt(4) per tile (T3+T4), XOR chunk^row&7 swizzle (T2), setprio (T5).
// LDS buffer layout (bytes): buf = (kt&1)<<16; regions of 16 KB:
//   A-lo(rows m0..m0+127) @0 | A-hi @16K | B-lo(n0..+127) @32K | B-hi @48K
// Region = 128 rows x 128 B; phys 16B-chunk = logical_chunk ^ (row&7).
// Staging stream per tile kt: P1->(kt+1).B-lo, P2->(kt+1).B-hi,
//   P3->(kt+2).A-lo, P4->(kt+2).A-hi; tile-end wait vmcnt(4).
// Race-freedom: A regions' last ds_read is P2, B regions' is P3; every stage
// of a region is >=1 barrier after that phase.
// FUSED=1: grid (12,64), z=x>>2 selects slab/weights/output, z==2 sigmoid, bf16.
// FUSED=0: grid (4,64), f32 out.
// ---------------------------------------------------------------------------
template<int FUSED>
__global__ __launch_bounds__(512, 2) void gemm256(
    const short* __restrict__ Abase,
    const short* __restrict__ Wbase,
    void* __restrict__ o0, void* __restrict__ o1, void* __restrict__ o2)
{
    __shared__ __align__(16) char lds[131072];

    const int tid  = threadIdx.x;
    const int lane = tid & 63;
    const int wv   = tid >> 6;
    const int wm   = wv >> 2, wn = wv & 3;       // 2 x 4 waves
    const int NT   = Cdim / 64;                  // 16 K-tiles

    int yt = blockIdx.y, z, nt;
    if (FUSED) { z = blockIdx.x >> 2; nt = blockIdx.x & 3; }
    else       { z = 0;               nt = blockIdx.x; }

    const short* A  = Abase + (size_t)z * SLAB;
    const short* Bm = Wbase + (size_t)z * Cdim * Cdim;
    const int m0 = yt * 256;
    const int n0 = nt * 256;

    f32x4 acc[8][4] = {};

    // per-lane read offsets (bytes)
    const int lm = lane & 15, lq = lane >> 4, lb7 = lane & 7;
    int ck[2];
    #pragma unroll
    for (int ks = 0; ks < 2; ++ks) ck[ks] = (((ks * 4 + lq) ^ lb7) << 4);
    int aoff[8];
    #pragma unroll
    for (int i = 0; i < 8; ++i) aoff[i] = (i * 16 + lm) * 128;
    int boff[4];
    #pragma unroll
    for (int j = 0; j < 4; ++j) boff[j] = ((wn & 1) * 64 + j * 16 + lm) * 128;
    const int aReg = wm << 14;                   // A-lo / A-hi
    const int bReg = 32768 + ((wn >> 1) << 14);  // B-lo / B-hi

    // stage one half-tile (2 x gload_lds, pre-swizzled global source)
    const int rlo  = tid >> 3;                   // 0..63
    const int clog = (tid & 7) ^ (rlo & 7);
    auto STAGE = [&](int tt, int part) {
        const short* mat = (part < 2) ? A : Bm;
        int rb = ((part < 2) ? m0 : n0) + ((part & 1) << 7);
        const short* g0 = mat + (size_t)(rb + rlo)      * Cdim + (tt << 6) + (clog << 3);
        const short* g1 = mat + (size_t)(rb + 64 + rlo) * Cdim + (tt << 6) + (clog << 3);
        char* l = lds + ((tt & 1) << 16) + (part << 14) + tid * 16;
        GLOAD_LDS16(g0, l);
        GLOAD_LDS16(g1, l + 8192);
    };

    // prologue: t0 all 4 halves + t1 A halves (12 loads); t0 resident
    STAGE(0, 0); STAGE(0, 1); STAGE(0, 2); STAGE(0, 3);
    STAGE(1, 0); STAGE(1, 1);
    asm volatile("s_waitcnt vmcnt(4)" ::: "memory");
    SBAR();

    bf16x8 a0[4][2], a4[4][2], bb[2][2];

    #pragma unroll 1
    for (int kt = 0; kt < NT; ++kt) {
        const char* base = lds + ((kt & 1) << 16);

        // ---- P1: read A frags 0-3 + B frags 0-1; MFMA Q(A0,B0) ----
        #pragma unroll
        for (int i = 0; i < 4; ++i)
            #pragma unroll
            for (int ks = 0; ks < 2; ++ks)
                a0[i][ks] = *(const bf16x8*)(base + aReg + aoff[i] + ck[ks]);
        #pragma unroll
        for (int j = 0; j < 2; ++j)
            #pragma unroll
            for (int ks = 0; ks < 2; ++ks)
                bb[j][ks] = *(const bf16x8*)(base + bReg + boff[j] + ck[ks]);
        if (kt + 1 < NT) STAGE(kt + 1, 2);
        SBAR();
        WAIT_LGKM0; SCHEDB();
        __builtin_amdgcn_s_setprio(1);
        #pragma unroll
        for (int i = 0; i < 4; ++i)
            #pragma unroll
            for (int j = 0; j < 2; ++j)
                #pragma unroll
                for (int ks = 0; ks < 2; ++ks)
                    acc[i][j] = __builtin_amdgcn_mfma_f32_16x16x32_bf16(
                        a0[i][ks], bb[j][ks], acc[i][j], 0, 0, 0);
        __builtin_amdgcn_s_setprio(0);
        SBAR();

        // ---- P2: read A frags 4-7 (last A reads); MFMA Q(A1,B0) ----
        #pragma unroll
        for (int i = 0; i < 4; ++i)
            #pragma unroll
            for (int ks = 0; ks < 2; ++ks)
                a4[i][ks] = *(const bf16x8*)(base + aReg + aoff[i + 4] + ck[ks]);
        if (kt + 1 < NT) STAGE(kt + 1, 3);
        SBAR();
        WAIT_LGKM0; SCHEDB();
        __builtin_amdgcn_s_setprio(1);
        #pragma unroll
        for (int i = 0; i < 4; ++i)
            #pragma unroll
            for (int j = 0; j < 2; ++j)
                #pragma unroll
                for (int ks = 0; ks < 2; ++ks)
                    acc[i + 4][j] = __builtin_amdgcn_mfma_f32_16x16x32_bf16(
                        a4[i][ks], bb[j][ks], acc[i + 4][j], 0, 0, 0);
        __builtin_amdgcn_s_setprio(0);
        SBAR();

        // ---- P3: read B frags 2-3 (last B reads); MFMA Q(A1,B1) ----
        #pragma unroll
        for (int j = 0; j < 2; ++j)
            #pragma unroll
            for (int ks = 0; ks < 2; ++ks)
                bb[j][ks] = *(const bf16x8*)(base + bReg + boff[j + 2] + ck[ks]);
        if (kt + 2 < NT) STAGE(kt + 2, 0);
        SBAR();
        WAIT_LGKM0; SCHEDB();
        __builtin_amdgcn_s_setprio(1);
        #pragma unroll
        for (int i = 0; i < 4; ++i)
            #pragma unroll
            for (int j = 0; j < 2; ++j)
                #pragma unroll
                for (int ks = 0; ks < 2; ++ks)
                    acc[i + 4][j + 2] = __builtin_amdgcn_mfma_f32_16x16x32_bf16(
                        a4[i][ks], bb[j][ks], acc[i + 4][j + 2], 0, 0, 0);
        __builtin_amdgcn_s_setprio(0);
        SBAR();

        // ---- P4: no reads (A0 held in regs); MFMA Q(A0,B1) ----
        if (kt + 2 < NT) STAGE(kt + 2, 1);
        SBAR();
        SCHEDB();
        __builtin_amdgcn_s_setprio(1);
        #pragma unroll
        for (int i = 0; i < 4; ++i)
            #pragma unroll
            for (int j = 0; j < 2; ++j)
                #pragma unroll
                for (int ks = 0; ks < 2; ++ks)
                    acc[i][j + 2] = __builtin_amdgcn_mfma_f32_16x16x32_bf16(
                        a0[i][ks], bb[j][ks], acc[i][j + 2], 0, 0, 0);
        __builtin_amdgcn_s_setprio(0);
        // counted tile-end wait: kt+1 fully resident; kt+2 A-halves in flight
        if      (kt + 2 < NT) { asm volatile("s_waitcnt vmcnt(4)" ::: "memory"); }
        else if (kt + 1 < NT) { asm volatile("s_waitcnt vmcnt(0)" ::: "memory"); }
        SBAR();
    }

    // epilogue: C/D layout col = lane&15, row = (lane>>4)*4 + r  [m89]
    int col0 = n0 + wn * 64 + lm;
    int row0 = m0 + wm * 128 + (lq << 2);
    short* outb = 0;
    if (FUSED) outb = (short*)((z == 0) ? o0 : (z == 1) ? o1 : o2);
    #pragma unroll
    for (int i = 0; i < 8; ++i) {
        #pragma unroll
        for (int j = 0; j < 4; ++j) {
            #pragma unroll
            for (int r = 0; r < 4; ++r) {
                int row = row0 + i * 16 + r;
                int cc  = col0 + j * 16;
                float vvv = acc[i][j][r];
                if (FUSED) {
                    if (z == 2) vvv = 1.f / (1.f + __expf(-vvv));
                    outb[(size_t)row * Cdim + cc] = f2bs(vvv);
                } else {
                    ((float*)o0)[(size_t)row * Cdim + cc] = vvv;
                }
            }
        }
    }
}

// ---------------------------------------------------------------------------
// wkv_chunked: chunked-parallel stable WKV scan; r is PRE-SIGMOIDED bf16.
// Block: CSUB=32 channels x NC=32 chunks = 1024 threads; grid = Bb * Cdim/32.
// ---------------------------------------------------------------------------
__global__ __launch_bounds__(1024) void wkv_chunked(
    const short* __restrict__ kb, const short* __restrict__ vb,
    const short* __restrict__ srb,
    const float* __restrict__ w, const float* __restrict__ u,
    short* __restrict__ rwkv)
{
    __shared__ float sp[NC][CSUB];
    __shared__ float sq[NC][CSUB];
    __shared__ float so[NC][CSUB];

    int tid = threadIdx.x;
    int cl  = tid & (CSUB - 1);
    int ch  = tid >> 5;                 // chunk index 0..NC-1
    int b   = blockIdx.x >> 5;          // grid = Bb * (Cdim/CSUB) = 8*32
    int cg  = blockIdx.x & 31;
    int c   = cg * CSUB + cl;

    float wexp = -__expf(w[c]);
    float uu   = u[c];
    size_t coff = (size_t)b * Tt * Cdim + (size_t)(ch * LCH) * Cdim + c;

    // ---- phase 1: local chunk summary from zero state ----
    float p = 0.f, q = 0.f, o = -1e30f;
    #pragma unroll 8
    for (int t = 0; t < LCH; ++t) {
        size_t off = coff + (size_t)t * Cdim;
        float kt = bs2f(kb[off]);
        float vt = bs2f(vb[off]);
        float wo  = wexp + o;
        float no  = fmaxf(wo, kt);
        float A   = __expf(wo - no);
        float B2  = __expf(kt - no);
        p = A * p + B2 * vt;
        q = A * q + B2;
        o = no;
    }
    sp[ch][cl] = p; sq[ch][cl] = q; so[ch][cl] = o;
    __syncthreads();

    // ---- phase 2: exclusive combine-scan over chunks (1 thread / channel) ----
    if (tid < CSUB) {
        float Ld = wexp * (float)LCH;   // decay of o over a full chunk
        float cp = 0.f, cq = 0.f, co = -1e30f;
        for (int j = 0; j < NC; ++j) {
            float lp = sp[j][tid], lq = sq[j][tid], lo = so[j][tid];
            sp[j][tid] = cp; sq[j][tid] = cq; so[j][tid] = co;  // incoming state
            float od = co + Ld;
            float no = fmaxf(od, lo);
            float A  = __expf(od - no);
            float B2 = __expf(lo - no);
            cp = A * cp + B2 * lp;
            cq = A * cq + B2 * lq;
            co = no;
        }
    }
    __syncthreads();

    // ---- phase 3: outputs from incoming state ----
    p = sp[ch][cl]; q = sq[ch][cl]; o = so[ch][cl];
    #pragma unroll 4
    for (int t = 0; t < LCH; ++t) {
        size_t off = coff + (size_t)t * Cdim;
        float kt = bs2f(kb[off]);
        float vt = bs2f(vb[off]);
        float sr = bs2f(srb[off]);       // sigmoid already applied in GEMM

        float uk  = uu + kt;
        float no  = fmaxf(o, uk);
        float Aa  = __expf(o - no);
        float Bc  = __expf(uk - no);
        float out = (Aa * p + Bc * vt) / (Aa * q + Bc);

        float wo  = wexp + o;
        float no2 = fmaxf(wo, kt);
        float A2  = __expf(wo - no2);
        float B2  = __expf(kt - no2);
        p = A2 * p + B2 * vt;
        q = A2 * q + B2;
        o = no2;

        rwkv[off] = f2bs(sr * out);
    }
}

// ---------------------------------------------------------------------------
extern "C" void kernel_launch(void* const* d_in, const int* in_sizes, int n_in,
                              void* d_out, int out_size, void* d_ws, size_t ws_size,
                              hipStream_t stream)
{
    const float* x    = (const float*)d_in[0];
    const float* w    = (const float*)d_in[1];
    const float* u    = (const float*)d_in[2];
    const float* mixk = (const float*)d_in[3];
    const float* mixv = (const float*)d_in[4];
    const float* mixr = (const float*)d_in[5];
    const float* Wk   = (const float*)d_in[6];
    const float* Wv   = (const float*)d_in[7];
    const float* Wr   = (const float*)d_in[8];
    const float* Wo   = (const float*)d_in[9];

    char* ws = (char*)d_ws;
    short* xmix = (short*)ws;                        // 3 slabs bf16 = 96 MiB
    short* wbf  = (short*)(ws + 3 * SLAB * 2);       // 4*C*C bf16 = 8 MiB
    short* rbuf = (short*)(ws + 3 * SLAB * 2 + (size_t)4 * Cdim * Cdim * 2); // 32 MiB
    short* rwkv = (short*)ws;                        // reuses dead xmix slab 0
    short* kbuf = (short*)d_out;                     // k,v bf16 live in d_out
    short* vbuf = kbuf + SLAB;                       // exactly fills 64 MiB

    prep_x<<<BT * Cdim / 8 / 256, 256, 0, stream>>>(x, mixk, mixv, mixr, xmix);
    prep_w<<<4 * Cdim * Cdim / 8 / 256, 256, 0, stream>>>(Wk, Wv, Wr, Wo, wbf);

    // fused k/v/r GEMM: grid (12,64) = 768 blocks
    dim3 gf(12, BT / 256);
    gemm256<1><<<gf, 512, 0, stream>>>(xmix, wbf, kbuf, vbuf, rbuf);

    wkv_chunked<<<Bb * (Cdim / CSUB), 1024, 0, stream>>>(kbuf, vbuf, rbuf, w, u, rwkv);

    // output GEMM: grid (4,64) = 256 blocks, f32 out
    dim3 go(Cdim / 256, BT / 256);
    gemm256<0><<<go, 512, 0, stream>>>(rwkv, wbf + 3 * (size_t)Cdim * Cdim,
                                       (float*)d_out, nullptr, nullptr);
}

// Round 6
// 245.977 us; speedup vs baseline: 1.2726x; 1.0404x over previous
//
#include <hip/hip_runtime.h>
#include <hip/hip_bf16.h>
#include <stdint.h>

#define Bb   8
#define Tt   2048
#define Cdim 1024
#define BT   16384   // Bb*Tt
#define SLAB ((size_t)BT * Cdim)

// chunked WKV scan geometry (round-3 proven: 66 us)
#define NC   32            // chunks per chain
#define LCH  64            // Tt / NC
#define CSUB 32            // channels per block

typedef __attribute__((ext_vector_type(4))) float f32x4;
typedef __attribute__((ext_vector_type(8))) short bf16x8;

__device__ inline short f2bs(float f) {
    union { __hip_bfloat16 h; short s; } u;
    u.h = __float2bfloat16(f);
    return u.s;
}
__device__ inline float bs2f(short s) {
    union { short s; __hip_bfloat16 h; } u;
    u.s = s;
    return __bfloat162float(u.h);
}

#define GLOAD_LDS16(g, l) __builtin_amdgcn_global_load_lds( \
    (const __attribute__((address_space(1))) void*)(g),     \
    (__attribute__((address_space(3))) void*)(l), 16, 0, 0)

#define SBAR()      __builtin_amdgcn_s_barrier()
#define WAIT_LGKM0  asm volatile("s_waitcnt lgkmcnt(0)" ::: "memory")
#define SCHEDB()    __builtin_amdgcn_sched_barrier(0)

// ---------------------------------------------------------------------------
// prep_x: xmix[z][m][c] = lerp(x_prev, x, mix_z)  (bf16), z in {k,v,r}
// ---------------------------------------------------------------------------
__global__ __launch_bounds__(256) void prep_x(
    const float* __restrict__ x,
    const float* __restrict__ mk,
    const float* __restrict__ mv,
    const float* __restrict__ mr,
    short* __restrict__ xmix)
{
    int idx = blockIdx.x * 256 + threadIdx.x;   // [0, BT*Cdim/8)
    int c8  = idx & (Cdim / 8 - 1);
    int m   = idx >> 7;                          // Cdim/8 == 128
    int c0  = c8 << 3;
    int t   = m & (Tt - 1);

    float xs[8], ps[8];
    const float4* xp = (const float4*)(x + (size_t)m * Cdim + c0);
    float4 xa = xp[0], xb = xp[1];
    xs[0]=xa.x; xs[1]=xa.y; xs[2]=xa.z; xs[3]=xa.w;
    xs[4]=xb.x; xs[5]=xb.y; xs[6]=xb.z; xs[7]=xb.w;
    if (t != 0) {
        const float4* pp = (const float4*)(x + (size_t)(m - 1) * Cdim + c0);
        float4 pa = pp[0], pb = pp[1];
        ps[0]=pa.x; ps[1]=pa.y; ps[2]=pa.z; ps[3]=pa.w;
        ps[4]=pb.x; ps[5]=pb.y; ps[6]=pb.z; ps[7]=pb.w;
    } else {
        #pragma unroll
        for (int j = 0; j < 8; ++j) ps[j] = 0.f;
    }

    const float* mixes[3] = {mk, mv, mr};
    #pragma unroll
    for (int z = 0; z < 3; ++z) {
        const float4* mp = (const float4*)(mixes[z] + c0);
        float4 ma = mp[0], mb = mp[1];
        float mm[8];
        mm[0]=ma.x; mm[1]=ma.y; mm[2]=ma.z; mm[3]=ma.w;
        mm[4]=mb.x; mm[5]=mb.y; mm[6]=mb.z; mm[7]=mb.w;
        bf16x8 o;
        #pragma unroll
        for (int j = 0; j < 8; ++j)
            o[j] = f2bs(ps[j] + mm[j] * (xs[j] - ps[j]));
        *(bf16x8*)(xmix + (size_t)z * SLAB + (size_t)m * Cdim + c0) = o;
    }
}

// ---------------------------------------------------------------------------
// prep_w: Wk|Wv|Wr|Wo f32 -> bf16, concatenated [4][C][C]
// ---------------------------------------------------------------------------
__global__ __launch_bounds__(256) void prep_w(
    const float* __restrict__ Wk, const float* __restrict__ Wv,
    const float* __restrict__ Wr, const float* __restrict__ Wo,
    short* __restrict__ wbf)
{
    int idx = blockIdx.x * 256 + threadIdx.x;       // [0, 4*C*C/8)
    int z   = idx >> 17;                            // C*C/8 == 131072
    int r   = idx & (Cdim * Cdim / 8 - 1);
    const float* src = (z == 0) ? Wk : (z == 1) ? Wv : (z == 2) ? Wr : Wo;
    const float4* sp = (const float4*)(src + (size_t)r * 8);
    float4 a = sp[0], b = sp[1];
    float v[8] = {a.x, a.y, a.z, a.w, b.x, b.y, b.z, b.w};
    bf16x8 o;
    #pragma unroll
    for (int j = 0; j < 8; ++j) o[j] = f2bs(v[j]);
    *(bf16x8*)(wbf + (size_t)z * Cdim * Cdim + (size_t)r * 8) = o;
}

// ---------------------------------------------------------------------------
// gemm256: m201-style 8-phase schedule (unchanged body from round 5).
// NEW (round 6): XCD-locality block mapping. Assuming dispatch round-robins
// XCDs by orig%8, XCD x owns yt in [8x, 8x+8); per-XCD sequence is z-major so
// each ~32-block co-resident round = {one z} x {8 yt} x {4 nt}:
//   A-tile shared by 4 nt-blocks (L2 hits), B panel shared by 8 yt-blocks.
// Per-XCD round working set ~= 4MB A + 2MB B ~= L2. Mapping is bijective, so
// a different dispatch policy only costs speed, never correctness.
// ---------------------------------------------------------------------------
template<int FUSED>
__global__ __launch_bounds__(512, 2) void gemm256(
    const short* __restrict__ Abase,
    const short* __restrict__ Wbase,
    void* __restrict__ o0, void* __restrict__ o1, void* __restrict__ o2)
{
    __shared__ __align__(16) char lds[131072];

    const int tid  = threadIdx.x;
    const int lane = tid & 63;
    const int wv   = tid >> 6;
    const int wm   = wv >> 2, wn = wv & 3;       // 2 x 4 waves
    const int NT   = Cdim / 64;                  // 16 K-tiles

    // XCD-locality remap
    int orig = blockIdx.y * (FUSED ? 12 : 4) + blockIdx.x;
    int xcd  = orig & 7;
    int s    = orig >> 3;                        // per-XCD sequence
    int z, nt, yt;
    if (FUSED) {                                 // s in [0,96)
        z  = s >> 5;                             // 32-block rounds: one z each
        int rem = s & 31;
        nt = rem & 3;
        yt = xcd * 8 + (rem >> 2);
    } else {                                     // s in [0,32)
        z  = 0;
        nt = s & 3;
        yt = xcd * 8 + (s >> 2);
    }

    const short* A  = Abase + (size_t)z * SLAB;
    const short* Bm = Wbase + (size_t)z * Cdim * Cdim;
    const int m0 = yt * 256;
    const int n0 = nt * 256;

    f32x4 acc[8][4] = {};

    // per-lane read offsets (bytes)
    const int lm = lane & 15, lq = lane >> 4, lb7 = lane & 7;
    int ck[2];
    #pragma unroll
    for (int ks = 0; ks < 2; ++ks) ck[ks] = (((ks * 4 + lq) ^ lb7) << 4);
    int aoff[8];
    #pragma unroll
    for (int i = 0; i < 8; ++i) aoff[i] = (i * 16 + lm) * 128;
    int boff[4];
    #pragma unroll
    for (int j = 0; j < 4; ++j) boff[j] = ((wn & 1) * 64 + j * 16 + lm) * 128;
    const int aReg = wm << 14;                   // A-lo / A-hi
    const int bReg = 32768 + ((wn >> 1) << 14);  // B-lo / B-hi

    // stage one half-tile (2 x gload_lds, pre-swizzled global source)
    const int rlo  = tid >> 3;                   // 0..63
    const int clog = (tid & 7) ^ (rlo & 7);
    auto STAGE = [&](int tt, int part) {
        const short* mat = (part < 2) ? A : Bm;
        int rb = ((part < 2) ? m0 : n0) + ((part & 1) << 7);
        const short* g0 = mat + (size_t)(rb + rlo)      * Cdim + (tt << 6) + (clog << 3);
        const short* g1 = mat + (size_t)(rb + 64 + rlo) * Cdim + (tt << 6) + (clog << 3);
        char* l = lds + ((tt & 1) << 16) + (part << 14) + tid * 16;
        GLOAD_LDS16(g0, l);
        GLOAD_LDS16(g1, l + 8192);
    };

    // prologue: t0 all 4 halves + t1 A halves (12 loads); t0 resident
    STAGE(0, 0); STAGE(0, 1); STAGE(0, 2); STAGE(0, 3);
    STAGE(1, 0); STAGE(1, 1);
    asm volatile("s_waitcnt vmcnt(4)" ::: "memory");
    SBAR();

    bf16x8 a0[4][2], a4[4][2], bb[2][2];

    #pragma unroll 1
    for (int kt = 0; kt < NT; ++kt) {
        const char* base = lds + ((kt & 1) << 16);

        // ---- P1: read A frags 0-3 + B frags 0-1; MFMA Q(A0,B0) ----
        #pragma unroll
        for (int i = 0; i < 4; ++i)
            #pragma unroll
            for (int ks = 0; ks < 2; ++ks)
                a0[i][ks] = *(const bf16x8*)(base + aReg + aoff[i] + ck[ks]);
        #pragma unroll
        for (int j = 0; j < 2; ++j)
            #pragma unroll
            for (int ks = 0; ks < 2; ++ks)
                bb[j][ks] = *(const bf16x8*)(base + bReg + boff[j] + ck[ks]);
        if (kt + 1 < NT) STAGE(kt + 1, 2);
        SBAR();
        WAIT_LGKM0; SCHEDB();
        __builtin_amdgcn_s_setprio(1);
        #pragma unroll
        for (int i = 0; i < 4; ++i)
            #pragma unroll
            for (int j = 0; j < 2; ++j)
                #pragma unroll
                for (int ks = 0; ks < 2; ++ks)
                    acc[i][j] = __builtin_amdgcn_mfma_f32_16x16x32_bf16(
                        a0[i][ks], bb[j][ks], acc[i][j], 0, 0, 0);
        __builtin_amdgcn_s_setprio(0);
        SBAR();

        // ---- P2: read A frags 4-7 (last A reads); MFMA Q(A1,B0) ----
        #pragma unroll
        for (int i = 0; i < 4; ++i)
            #pragma unroll
            for (int ks = 0; ks < 2; ++ks)
                a4[i][ks] = *(const bf16x8*)(base + aReg + aoff[i + 4] + ck[ks]);
        if (kt + 1 < NT) STAGE(kt + 1, 3);
        SBAR();
        WAIT_LGKM0; SCHEDB();
        __builtin_amdgcn_s_setprio(1);
        #pragma unroll
        for (int i = 0; i < 4; ++i)
            #pragma unroll
            for (int j = 0; j < 2; ++j)
                #pragma unroll
                for (int ks = 0; ks < 2; ++ks)
                    acc[i + 4][j] = __builtin_amdgcn_mfma_f32_16x16x32_bf16(
                        a4[i][ks], bb[j][ks], acc[i + 4][j], 0, 0, 0);
        __builtin_amdgcn_s_setprio(0);
        SBAR();

        // ---- P3: read B frags 2-3 (last B reads); MFMA Q(A1,B1) ----
        #pragma unroll
        for (int j = 0; j < 2; ++j)
            #pragma unroll
            for (int ks = 0; ks < 2; ++ks)
                bb[j][ks] = *(const bf16x8*)(base + bReg + boff[j + 2] + ck[ks]);
        if (kt + 2 < NT) STAGE(kt + 2, 0);
        SBAR();
        WAIT_LGKM0; SCHEDB();
        __builtin_amdgcn_s_setprio(1);
        #pragma unroll
        for (int i = 0; i < 4; ++i)
            #pragma unroll
            for (int j = 0; j < 2; ++j)
                #pragma unroll
                for (int ks = 0; ks < 2; ++ks)
                    acc[i + 4][j + 2] = __builtin_amdgcn_mfma_f32_16x16x32_bf16(
                        a4[i][ks], bb[j][ks], acc[i + 4][j + 2], 0, 0, 0);
        __builtin_amdgcn_s_setprio(0);
        SBAR();

        // ---- P4: no reads (A0 held in regs); MFMA Q(A0,B1) ----
        if (kt + 2 < NT) STAGE(kt + 2, 1);
        SBAR();
        SCHEDB();
        __builtin_amdgcn_s_setprio(1);
        #pragma unroll
        for (int i = 0; i < 4; ++i)
            #pragma unroll
            for (int j = 0; j < 2; ++j)
                #pragma unroll
                for (int ks = 0; ks < 2; ++ks)
                    acc[i][j + 2] = __builtin_amdgcn_mfma_f32_16x16x32_bf16(
                        a0[i][ks], bb[j][ks], acc[i][j + 2], 0, 0, 0);
        __builtin_amdgcn_s_setprio(0);
        // counted tile-end wait: kt+1 fully resident; kt+2 A-halves in flight
        if      (kt + 2 < NT) { asm volatile("s_waitcnt vmcnt(4)" ::: "memory"); }
        else if (kt + 1 < NT) { asm volatile("s_waitcnt vmcnt(0)" ::: "memory"); }
        SBAR();
    }

    // epilogue: C/D layout col = lane&15, row = (lane>>4)*4 + r  [m89]
    int col0 = n0 + wn * 64 + lm;
    int row0 = m0 + wm * 128 + (lq << 2);
    short* outb = 0;
    if (FUSED) outb = (short*)((z == 0) ? o0 : (z == 1) ? o1 : o2);
    #pragma unroll
    for (int i = 0; i < 8; ++i) {
        #pragma unroll
        for (int j = 0; j < 4; ++j) {
            #pragma unroll
            for (int r = 0; r < 4; ++r) {
                int row = row0 + i * 16 + r;
                int cc  = col0 + j * 16;
                float vvv = acc[i][j][r];
                if (FUSED) {
                    if (z == 2) vvv = 1.f / (1.f + __expf(-vvv));
                    outb[(size_t)row * Cdim + cc] = f2bs(vvv);
                } else {
                    ((float*)o0)[(size_t)row * Cdim + cc] = vvv;
                }
            }
        }
    }
}

// ---------------------------------------------------------------------------
// wkv_chunked: chunked-parallel stable WKV scan; r is PRE-SIGMOIDED bf16.
// Block: CSUB=32 channels x NC=32 chunks = 1024 threads; grid = Bb * Cdim/32.
// ---------------------------------------------------------------------------
__global__ __launch_bounds__(1024) void wkv_chunked(
    const short* __restrict__ kb, const short* __restrict__ vb,
    const short* __restrict__ srb,
    const float* __restrict__ w, const float* __restrict__ u,
    short* __restrict__ rwkv)
{
    __shared__ float sp[NC][CSUB];
    __shared__ float sq[NC][CSUB];
    __shared__ float so[NC][CSUB];

    int tid = threadIdx.x;
    int cl  = tid & (CSUB - 1);
    int ch  = tid >> 5;                 // chunk index 0..NC-1
    int b   = blockIdx.x >> 5;          // grid = Bb * (Cdim/CSUB) = 8*32
    int cg  = blockIdx.x & 31;
    int c   = cg * CSUB + cl;

    float wexp = -__expf(w[c]);
    float uu   = u[c];
    size_t coff = (size_t)b * Tt * Cdim + (size_t)(ch * LCH) * Cdim + c;

    // ---- phase 1: local chunk summary from zero state ----
    float p = 0.f, q = 0.f, o = -1e30f;
    #pragma unroll 8
    for (int t = 0; t < LCH; ++t) {
        size_t off = coff + (size_t)t * Cdim;
        float kt = bs2f(kb[off]);
        float vt = bs2f(vb[off]);
        float wo  = wexp + o;
        float no  = fmaxf(wo, kt);
        float A   = __expf(wo - no);
        float B2  = __expf(kt - no);
        p = A * p + B2 * vt;
        q = A * q + B2;
        o = no;
    }
    sp[ch][cl] = p; sq[ch][cl] = q; so[ch][cl] = o;
    __syncthreads();

    // ---- phase 2: exclusive combine-scan over chunks (1 thread / channel) ----
    if (tid < CSUB) {
        float Ld = wexp * (float)LCH;   // decay of o over a full chunk
        float cp = 0.f, cq = 0.f, co = -1e30f;
        for (int j = 0; j < NC; ++j) {
            float lp = sp[j][tid], lq = sq[j][tid], lo = so[j][tid];
            sp[j][tid] = cp; sq[j][tid] = cq; so[j][tid] = co;  // incoming state
            float od = co + Ld;
            float no = fmaxf(od, lo);
            float A  = __expf(od - no);
            float B2 = __expf(lo - no);
            cp = A * cp + B2 * lp;
            cq = A * cq + B2 * lq;
            co = no;
        }
    }
    __syncthreads();

    // ---- phase 3: outputs from incoming state ----
    p = sp[ch][cl]; q = sq[ch][cl]; o = so[ch][cl];
    #pragma unroll 8
    for (int t = 0; t < LCH; ++t) {
        size_t off = coff + (size_t)t * Cdim;
        float kt = bs2f(kb[off]);
        float vt = bs2f(vb[off]);
        float sr = bs2f(srb[off]);       // sigmoid already applied in GEMM

        float uk  = uu + kt;
        float no  = fmaxf(o, uk);
        float Aa  = __expf(o - no);
        float Bc  = __expf(uk - no);
        float out = (Aa * p + Bc * vt) / (Aa * q + Bc);

        float wo  = wexp + o;
        float no2 = fmaxf(wo, kt);
        float A2  = __expf(wo - no2);
        float B2  = __expf(kt - no2);
        p = A2 * p + B2 * vt;
        q = A2 * q + B2;
        o = no2;

        rwkv[off] = f2bs(sr * out);
    }
}

// ---------------------------------------------------------------------------
extern "C" void kernel_launch(void* const* d_in, const int* in_sizes, int n_in,
                              void* d_out, int out_size, void* d_ws, size_t ws_size,
                              hipStream_t stream)
{
    const float* x    = (const float*)d_in[0];
    const float* w    = (const float*)d_in[1];
    const float* u    = (const float*)d_in[2];
    const float* mixk = (const float*)d_in[3];
    const float* mixv = (const float*)d_in[4];
    const float* mixr = (const float*)d_in[5];
    const float* Wk   = (const float*)d_in[6];
    const float* Wv   = (const float*)d_in[7];
    const float* Wr   = (const float*)d_in[8];
    const float* Wo   = (const float*)d_in[9];

    char* ws = (char*)d_ws;
    short* xmix = (short*)ws;                        // 3 slabs bf16 = 96 MiB
    short* wbf  = (short*)(ws + 3 * SLAB * 2);       // 4*C*C bf16 = 8 MiB
    short* rbuf = (short*)(ws + 3 * SLAB * 2 + (size_t)4 * Cdim * Cdim * 2); // 32 MiB
    short* rwkv = (short*)ws;                        // reuses dead xmix slab 0
    short* kbuf = (short*)d_out;                     // k,v bf16 live in d_out
    short* vbuf = kbuf + SLAB;                       // exactly fills 64 MiB

    prep_x<<<BT * Cdim / 8 / 256, 256, 0, stream>>>(x, mixk, mixv, mixr, xmix);
    prep_w<<<4 * Cdim * Cdim / 8 / 256, 256, 0, stream>>>(Wk, Wv, Wr, Wo, wbf);

    // fused k/v/r GEMM: grid (12,64) = 768 blocks
    dim3 gf(12, BT / 256);
    gemm256<1><<<gf, 512, 0, stream>>>(xmix, wbf, kbuf, vbuf, rbuf);

    wkv_chunked<<<Bb * (Cdim / CSUB), 1024, 0, stream>>>(kbuf, vbuf, rbuf, w, u, rwkv);

    // output GEMM: grid (4,64) = 256 blocks, f32 out
    dim3 go(Cdim / 256, BT / 256);
    gemm256<0><<<go, 512, 0, stream>>>(rwkv, wbf + 3 * (size_t)Cdim * Cdim,
                                       (float*)d_out, nullptr, nullptr);
}

// Round 7
// 240.931 us; speedup vs baseline: 1.2993x; 1.0209x over previous
//
#include <hip/hip_runtime.h>
#include <hip/hip_bf16.h>
#include <stdint.h>

#define Bb   8
#define Tt   2048
#define Cdim 1024
#define BT   16384   // Bb*Tt
#define SLAB ((size_t)BT * Cdim)

// chunked WKV scan geometry (round-3 proven)
#define NC   32            // chunks per chain
#define LCH  64            // Tt / NC
#define CSUB 32            // channels per block

typedef __attribute__((ext_vector_type(4))) float f32x4;
typedef __attribute__((ext_vector_type(8))) short bf16x8;

__device__ inline short f2bs(float f) {
    union { __hip_bfloat16 h; short s; } u;
    u.h = __float2bfloat16(f);
    return u.s;
}
__device__ inline float bs2f(short s) {
    union { short s; __hip_bfloat16 h; } u;
    u.s = s;
    return __bfloat162float(u.h);
}

#define GLOAD_LDS16(g, l) __builtin_amdgcn_global_load_lds( \
    (const __attribute__((address_space(1))) void*)(g),     \
    (__attribute__((address_space(3))) void*)(l), 16, 0, 0)

#define SBAR()      __builtin_amdgcn_s_barrier()

// ---------------------------------------------------------------------------
// prep_x: xmix[z][m][c] = lerp(x_prev, x, mix_z)  (bf16), z in {k,v,r}
// ---------------------------------------------------------------------------
__global__ __launch_bounds__(256) void prep_x(
    const float* __restrict__ x,
    const float* __restrict__ mk,
    const float* __restrict__ mv,
    const float* __restrict__ mr,
    short* __restrict__ xmix)
{
    int idx = blockIdx.x * 256 + threadIdx.x;   // [0, BT*Cdim/8)
    int c8  = idx & (Cdim / 8 - 1);
    int m   = idx >> 7;                          // Cdim/8 == 128
    int c0  = c8 << 3;
    int t   = m & (Tt - 1);

    float xs[8], ps[8];
    const float4* xp = (const float4*)(x + (size_t)m * Cdim + c0);
    float4 xa = xp[0], xb = xp[1];
    xs[0]=xa.x; xs[1]=xa.y; xs[2]=xa.z; xs[3]=xa.w;
    xs[4]=xb.x; xs[5]=xb.y; xs[6]=xb.z; xs[7]=xb.w;
    if (t != 0) {
        const float4* pp = (const float4*)(x + (size_t)(m - 1) * Cdim + c0);
        float4 pa = pp[0], pb = pp[1];
        ps[0]=pa.x; ps[1]=pa.y; ps[2]=pa.z; ps[3]=pa.w;
        ps[4]=pb.x; ps[5]=pb.y; ps[6]=pb.z; ps[7]=pb.w;
    } else {
        #pragma unroll
        for (int j = 0; j < 8; ++j) ps[j] = 0.f;
    }

    const float* mixes[3] = {mk, mv, mr};
    #pragma unroll
    for (int z = 0; z < 3; ++z) {
        const float4* mp = (const float4*)(mixes[z] + c0);
        float4 ma = mp[0], mb = mp[1];
        float mm[8];
        mm[0]=ma.x; mm[1]=ma.y; mm[2]=ma.z; mm[3]=ma.w;
        mm[4]=mb.x; mm[5]=mb.y; mm[6]=mb.z; mm[7]=mb.w;
        bf16x8 o;
        #pragma unroll
        for (int j = 0; j < 8; ++j)
            o[j] = f2bs(ps[j] + mm[j] * (xs[j] - ps[j]));
        *(bf16x8*)(xmix + (size_t)z * SLAB + (size_t)m * Cdim + c0) = o;
    }
}

// ---------------------------------------------------------------------------
// prep_w: Wk|Wv|Wr|Wo f32 -> bf16, concatenated [4][C][C]
// ---------------------------------------------------------------------------
__global__ __launch_bounds__(256) void prep_w(
    const float* __restrict__ Wk, const float* __restrict__ Wv,
    const float* __restrict__ Wr, const float* __restrict__ Wo,
    short* __restrict__ wbf)
{
    int idx = blockIdx.x * 256 + threadIdx.x;       // [0, 4*C*C/8)
    int z   = idx >> 17;                            // C*C/8 == 131072
    int r   = idx & (Cdim * Cdim / 8 - 1);
    const float* src = (z == 0) ? Wk : (z == 1) ? Wv : (z == 2) ? Wr : Wo;
    const float4* sp = (const float4*)(src + (size_t)r * 8);
    float4 a = sp[0], b = sp[1];
    float v[8] = {a.x, a.y, a.z, a.w, b.x, b.y, b.z, b.w};
    bf16x8 o;
    #pragma unroll
    for (int j = 0; j < 8; ++j) o[j] = f2bs(v[j]);
    *(bf16x8*)(wbf + (size_t)z * Cdim * Cdim + (size_t)r * 8) = o;
}

// ---------------------------------------------------------------------------
// gemm256: 256x256 tile, BK=64, 8 waves (2Mx4N), double-buffered LDS,
// XCD-locality mapping (r6), XOR chunk^row&7 swizzle (T2, conflict-free).
// ROUND 7: read-ahead K-loop — P1 issues ALL A reads + B01, P2 issues B23,
// so each MFMA cluster waits only on reads issued >=1 cluster earlier
// (compiler emits counted lgkmcnt); ONE barrier per phase (wave skew < 1
// phase gives cross-wave LDS/MFMA overlap); ks-outer MFMA order (dependent
// accumulator pairs 8 apart). Staging & tile-end vmcnt(4) unchanged.
// Hazard audit (skew < 1 phase due to per-phase barrier):
//   A-lo: reads issued+consumed P1, overwritten P3 (stage kt+2) -> safe
//   A-hi: reads issued P1, consumed P2-MFMA, overwritten P4    -> safe
//   B: staged into opposite buffer (kt+1)                       -> safe
//   kt+1.B resident: tile-end vmcnt(4) leaves only kt+2.A in flight.
// ---------------------------------------------------------------------------
template<int FUSED>
__global__ __launch_bounds__(512, 2) void gemm256(
    const short* __restrict__ Abase,
    const short* __restrict__ Wbase,
    void* __restrict__ o0, void* __restrict__ o1, void* __restrict__ o2)
{
    __shared__ __align__(16) char lds[131072];

    const int tid  = threadIdx.x;
    const int lane = tid & 63;
    const int wv   = tid >> 6;
    const int wm   = wv >> 2, wn = wv & 3;       // 2 x 4 waves
    const int NT   = Cdim / 64;                  // 16 K-tiles

    // XCD-locality remap (r6): XCD x owns yt in [8x,8x+8), z-major rounds
    int orig = blockIdx.y * (FUSED ? 12 : 4) + blockIdx.x;
    int xcd  = orig & 7;
    int s    = orig >> 3;
    int z, nt, yt;
    if (FUSED) {
        z  = s >> 5;
        int rem = s & 31;
        nt = rem & 3;
        yt = xcd * 8 + (rem >> 2);
    } else {
        z  = 0;
        nt = s & 3;
        yt = xcd * 8 + (s >> 2);
    }

    const short* A  = Abase + (size_t)z * SLAB;
    const short* Bm = Wbase + (size_t)z * Cdim * Cdim;
    const int m0 = yt * 256;
    const int n0 = nt * 256;

    f32x4 acc[8][4] = {};

    // per-lane read offsets (bytes)
    const int lm = lane & 15, lq = lane >> 4, lb7 = lane & 7;
    int ck[2];
    #pragma unroll
    for (int ks = 0; ks < 2; ++ks) ck[ks] = (((ks * 4 + lq) ^ lb7) << 4);
    int aoff[8];
    #pragma unroll
    for (int i = 0; i < 8; ++i) aoff[i] = (i * 16 + lm) * 128;
    int boff[4];
    #pragma unroll
    for (int j = 0; j < 4; ++j) boff[j] = ((wn & 1) * 64 + j * 16 + lm) * 128;
    const int aReg = wm << 14;                   // A-lo / A-hi
    const int bReg = 32768 + ((wn >> 1) << 14);  // B-lo / B-hi

    // stage one half-tile (2 x gload_lds, pre-swizzled global source)
    const int rlo  = tid >> 3;                   // 0..63
    const int clog = (tid & 7) ^ (rlo & 7);
    auto STAGE = [&](int tt, int part) {
        const short* mat = (part < 2) ? A : Bm;
        int rb = ((part < 2) ? m0 : n0) + ((part & 1) << 7);
        const short* g0 = mat + (size_t)(rb + rlo)      * Cdim + (tt << 6) + (clog << 3);
        const short* g1 = mat + (size_t)(rb + 64 + rlo) * Cdim + (tt << 6) + (clog << 3);
        char* l = lds + ((tt & 1) << 16) + (part << 14) + tid * 16;
        GLOAD_LDS16(g0, l);
        GLOAD_LDS16(g1, l + 8192);
    };

    // prologue: t0 all 4 halves + t1 A halves; t0 resident, t1.A in flight
    STAGE(0, 0); STAGE(0, 1); STAGE(0, 2); STAGE(0, 3);
    STAGE(1, 0); STAGE(1, 1);
    asm volatile("s_waitcnt vmcnt(4)" ::: "memory");
    SBAR();

    bf16x8 a0[4][2], a4[4][2], b01[2][2], b23[2][2];

    #pragma unroll 1
    for (int kt = 0; kt < NT; ++kt) {
        const char* base = lds + ((kt & 1) << 16);

        // ---- P1: issue a0, b01, a4 reads; stage (kt+1).B-lo; MFMA Q(A0,B0)
        #pragma unroll
        for (int i = 0; i < 4; ++i)
            #pragma unroll
            for (int ks = 0; ks < 2; ++ks)
                a0[i][ks] = *(const bf16x8*)(base + aReg + aoff[i] + ck[ks]);
        #pragma unroll
        for (int j = 0; j < 2; ++j)
            #pragma unroll
            for (int ks = 0; ks < 2; ++ks)
                b01[j][ks] = *(const bf16x8*)(base + bReg + boff[j] + ck[ks]);
        #pragma unroll
        for (int i = 0; i < 4; ++i)
            #pragma unroll
            for (int ks = 0; ks < 2; ++ks)
                a4[i][ks] = *(const bf16x8*)(base + aReg + aoff[i + 4] + ck[ks]);
        if (kt + 1 < NT) STAGE(kt + 1, 2);
        __builtin_amdgcn_s_setprio(1);
        #pragma unroll
        for (int ks = 0; ks < 2; ++ks)
            #pragma unroll
            for (int i = 0; i < 4; ++i)
                #pragma unroll
                for (int j = 0; j < 2; ++j)
                    acc[i][j] = __builtin_amdgcn_mfma_f32_16x16x32_bf16(
                        a0[i][ks], b01[j][ks], acc[i][j], 0, 0, 0);
        __builtin_amdgcn_s_setprio(0);
        SBAR();

        // ---- P2: issue b23 reads; stage (kt+1).B-hi; MFMA Q(A1,B0) ----
        #pragma unroll
        for (int j = 0; j < 2; ++j)
            #pragma unroll
            for (int ks = 0; ks < 2; ++ks)
                b23[j][ks] = *(const bf16x8*)(base + bReg + boff[j + 2] + ck[ks]);
        if (kt + 1 < NT) STAGE(kt + 1, 3);
        __builtin_amdgcn_s_setprio(1);
        #pragma unroll
        for (int ks = 0; ks < 2; ++ks)
            #pragma unroll
            for (int i = 0; i < 4; ++i)
                #pragma unroll
                for (int j = 0; j < 2; ++j)
                    acc[i + 4][j] = __builtin_amdgcn_mfma_f32_16x16x32_bf16(
                        a4[i][ks], b01[j][ks], acc[i + 4][j], 0, 0, 0);
        __builtin_amdgcn_s_setprio(0);
        SBAR();

        // ---- P3: stage (kt+2).A-lo; MFMA Q(A1,B1) (all regs held) ----
        if (kt + 2 < NT) STAGE(kt + 2, 0);
        __builtin_amdgcn_s_setprio(1);
        #pragma unroll
        for (int ks = 0; ks < 2; ++ks)
            #pragma unroll
            for (int i = 0; i < 4; ++i)
                #pragma unroll
                for (int j = 0; j < 2; ++j)
                    acc[i + 4][j + 2] = __builtin_amdgcn_mfma_f32_16x16x32_bf16(
                        a4[i][ks], b23[j][ks], acc[i + 4][j + 2], 0, 0, 0);
        __builtin_amdgcn_s_setprio(0);
        SBAR();

        // ---- P4: stage (kt+2).A-hi; MFMA Q(A0,B1) (all regs held) ----
        if (kt + 2 < NT) STAGE(kt + 2, 1);
        __builtin_amdgcn_s_setprio(1);
        #pragma unroll
        for (int ks = 0; ks < 2; ++ks)
            #pragma unroll
            for (int i = 0; i < 4; ++i)
                #pragma unroll
                for (int j = 0; j < 2; ++j)
                    acc[i][j + 2] = __builtin_amdgcn_mfma_f32_16x16x32_bf16(
                        a0[i][ks], b23[j][ks], acc[i][j + 2], 0, 0, 0);
        __builtin_amdgcn_s_setprio(0);
        // counted tile-end wait: confirms (kt+1).B (and older); leaves
        // (kt+2).A halves (4 loads) in flight.
        if      (kt + 2 < NT) { asm volatile("s_waitcnt vmcnt(4)" ::: "memory"); }
        else if (kt + 1 < NT) { asm volatile("s_waitcnt vmcnt(0)" ::: "memory"); }
        SBAR();
    }

    // epilogue: C/D layout col = lane&15, row = (lane>>4)*4 + r  [m89]
    int col0 = n0 + wn * 64 + lm;
    int row0 = m0 + wm * 128 + (lq << 2);
    short* outb = 0;
    if (FUSED) outb = (short*)((z == 0) ? o0 : (z == 1) ? o1 : o2);
    #pragma unroll
    for (int i = 0; i < 8; ++i) {
        #pragma unroll
        for (int j = 0; j < 4; ++j) {
            #pragma unroll
            for (int r = 0; r < 4; ++r) {
                int row = row0 + i * 16 + r;
                int cc  = col0 + j * 16;
                float vvv = acc[i][j][r];
                if (FUSED) {
                    if (z == 2) vvv = 1.f / (1.f + __expf(-vvv));
                    outb[(size_t)row * Cdim + cc] = f2bs(vvv);
                } else {
                    ((float*)o0)[(size_t)row * Cdim + cc] = vvv;
                }
            }
        }
    }
}

// ---------------------------------------------------------------------------
// wkv_chunked: chunked-parallel stable WKV scan; r is PRE-SIGMOIDED bf16.
// Block: CSUB=32 channels x NC=32 chunks = 1024 threads; grid = Bb * Cdim/32.
// ---------------------------------------------------------------------------
__global__ __launch_bounds__(1024) void wkv_chunked(
    const short* __restrict__ kb, const short* __restrict__ vb,
    const short* __restrict__ srb,
    const float* __restrict__ w, const float* __restrict__ u,
    short* __restrict__ rwkv)
{
    __shared__ float sp[NC][CSUB];
    __shared__ float sq[NC][CSUB];
    __shared__ float so[NC][CSUB];

    int tid = threadIdx.x;
    int cl  = tid & (CSUB - 1);
    int ch  = tid >> 5;                 // chunk index 0..NC-1
    int b   = blockIdx.x >> 5;          // grid = Bb * (Cdim/CSUB) = 8*32
    int cg  = blockIdx.x & 31;
    int c   = cg * CSUB + cl;

    float wexp = -__expf(w[c]);
    float uu   = u[c];
    size_t coff = (size_t)b * Tt * Cdim + (size_t)(ch * LCH) * Cdim + c;

    // ---- phase 1: local chunk summary from zero state ----
    float p = 0.f, q = 0.f, o = -1e30f;
    #pragma unroll 8
    for (int t = 0; t < LCH; ++t) {
        size_t off = coff + (size_t)t * Cdim;
        float kt = bs2f(kb[off]);
        float vt = bs2f(vb[off]);
        float wo  = wexp + o;
        float no  = fmaxf(wo, kt);
        float A   = __expf(wo - no);
        float B2  = __expf(kt - no);
        p = A * p + B2 * vt;
        q = A * q + B2;
        o = no;
    }
    sp[ch][cl] = p; sq[ch][cl] = q; so[ch][cl] = o;
    __syncthreads();

    // ---- phase 2: exclusive combine-scan over chunks (1 thread / channel) ----
    if (tid < CSUB) {
        float Ld = wexp * (float)LCH;   // decay of o over a full chunk
        float cp = 0.f, cq = 0.f, co = -1e30f;
        for (int j = 0; j < NC; ++j) {
            float lp = sp[j][tid], lq = sq[j][tid], lo = so[j][tid];
            sp[j][tid] = cp; sq[j][tid] = cq; so[j][tid] = co;  // incoming state
            float od = co + Ld;
            float no = fmaxf(od, lo);
            float A  = __expf(od - no);
            float B2 = __expf(lo - no);
            cp = A * cp + B2 * lp;
            cq = A * cq + B2 * lq;
            co = no;
        }
    }
    __syncthreads();

    // ---- phase 3: outputs from incoming state ----
    p = sp[ch][cl]; q = sq[ch][cl]; o = so[ch][cl];
    #pragma unroll 8
    for (int t = 0; t < LCH; ++t) {
        size_t off = coff + (size_t)t * Cdim;
        float kt = bs2f(kb[off]);
        float vt = bs2f(vb[off]);
        float sr = bs2f(srb[off]);       // sigmoid already applied in GEMM

        float uk  = uu + kt;
        float no  = fmaxf(o, uk);
        float Aa  = __expf(o - no);
        float Bc  = __expf(uk - no);
        float out = (Aa * p + Bc * vt) / (Aa * q + Bc);

        float wo  = wexp + o;
        float no2 = fmaxf(wo, kt);
        float A2  = __expf(wo - no2);
        float B2  = __expf(kt - no2);
        p = A2 * p + B2 * vt;
        q = A2 * q + B2;
        o = no2;

        rwkv[off] = f2bs(sr * out);
    }
}

// ---------------------------------------------------------------------------
extern "C" void kernel_launch(void* const* d_in, const int* in_sizes, int n_in,
                              void* d_out, int out_size, void* d_ws, size_t ws_size,
                              hipStream_t stream)
{
    const float* x    = (const float*)d_in[0];
    const float* w    = (const float*)d_in[1];
    const float* u    = (const float*)d_in[2];
    const float* mixk = (const float*)d_in[3];
    const float* mixv = (const float*)d_in[4];
    const float* mixr = (const float*)d_in[5];
    const float* Wk   = (const float*)d_in[6];
    const float* Wv   = (const float*)d_in[7];
    const float* Wr   = (const float*)d_in[8];
    const float* Wo   = (const float*)d_in[9];

    char* ws = (char*)d_ws;
    short* xmix = (short*)ws;                        // 3 slabs bf16 = 96 MiB
    short* wbf  = (short*)(ws + 3 * SLAB * 2);       // 4*C*C bf16 = 8 MiB
    short* rbuf = (short*)(ws + 3 * SLAB * 2 + (size_t)4 * Cdim * Cdim * 2); // 32 MiB
    short* rwkv = (short*)ws;                        // reuses dead xmix slab 0
    short* kbuf = (short*)d_out;                     // k,v bf16 live in d_out
    short* vbuf = kbuf + SLAB;                       // exactly fills 64 MiB

    prep_x<<<BT * Cdim / 8 / 256, 256, 0, stream>>>(x, mixk, mixv, mixr, xmix);
    prep_w<<<4 * Cdim * Cdim / 8 / 256, 256, 0, stream>>>(Wk, Wv, Wr, Wo, wbf);

    // fused k/v/r GEMM: grid (12,64) = 768 blocks
    dim3 gf(12, BT / 256);
    gemm256<1><<<gf, 512, 0, stream>>>(xmix, wbf, kbuf, vbuf, rbuf);

    wkv_chunked<<<Bb * (Cdim / CSUB), 1024, 0, stream>>>(kbuf, vbuf, rbuf, w, u, rwkv);

    // output GEMM: grid (4,64) = 256 blocks, f32 out
    dim3 go(Cdim / 256, BT / 256);
    gemm256<0><<<go, 512, 0, stream>>>(rwkv, wbf + 3 * (size_t)Cdim * Cdim,
                                       (float*)d_out, nullptr, nullptr);
}